// Round 1
// baseline (2175.315 us; speedup 1.0000x reference)
//
#include <hip/hip_runtime.h>

// Problem constants (from reference): N=32, C=192, T=256, V=25, S=3, mid=64
#define TV 6400           // T*V
#define NCH 192           // C
#define D3 576            // 3*C

typedef unsigned short u16;
typedef unsigned int   u32;

__device__ __forceinline__ float bf2f(u32 h) {
    return __uint_as_float(h << 16);
}
__device__ __forceinline__ u16 f2bf(float f) {
    u32 u = __float_as_uint(f);
    return (u16)((u + 0x7FFFu + ((u >> 16) & 1u)) >> 16);
}

// ---------------------------------------------------------------------------
// Kernel 1: QKV projection. qkv[n,d,t,v] = sum_c x[n,c,t,v]*w_in[d,c] + b_in[d]
// GEMM per n: M=576 (d, tiles of 64 == one e-group), N=6400 (p=(t,v), tiles 128), K=192
// Output bf16 in native [n][d][t*25+v] layout (fully coalesced uint4 stores).
// ---------------------------------------------------------------------------
__global__ __launch_bounds__(256) void k_qkv(const float* __restrict__ x,
                                             const float* __restrict__ w_in,
                                             const float* __restrict__ b_in,
                                             u16* __restrict__ qkv) {
    const int n = blockIdx.z, d0 = blockIdx.y * 64, p0 = blockIdx.x * 128;
    const int tx = threadIdx.x, ty = threadIdx.y, tid = ty * 16 + tx;

    __shared__ float Ws[16][68];   // [k][d], pad 68 (odd*4 banks) for conflict-free writes
    __shared__ float Xs[16][128];  // [k][p]

    float acc[4][8];
#pragma unroll
    for (int i = 0; i < 4; i++)
#pragma unroll
        for (int j = 0; j < 8; j++) acc[i][j] = 0.f;

    const float* xn = x + (size_t)n * NCH * TV;

    for (int c0 = 0; c0 < 192; c0 += 16) {
        // W tile: 64d x 16k, coalesced along c
#pragma unroll
        for (int r = 0; r < 4; r++) {
            int l = tid + 256 * r;
            int kk = l & 15, dd = l >> 4;
            Ws[kk][dd] = w_in[(size_t)(d0 + dd) * 192 + c0 + kk];
        }
        // X tile: 16k x 128p, float4 coalesced
#pragma unroll
        for (int r = 0; r < 2; r++) {
            int l = tid + 256 * r;
            int pp4 = l & 31, kk = l >> 5;
            float4 v = *(const float4*)(xn + (size_t)(c0 + kk) * TV + p0 + pp4 * 4);
            *(float4*)&Xs[kk][pp4 * 4] = v;
        }
        __syncthreads();
#pragma unroll
        for (int kk = 0; kk < 16; kk++) {
            float4 a4 = *(const float4*)&Ws[kk][ty * 4];
            float4 b0 = *(const float4*)&Xs[kk][tx * 8];
            float4 b1 = *(const float4*)&Xs[kk][tx * 8 + 4];
            float a[4] = {a4.x, a4.y, a4.z, a4.w};
            float b[8] = {b0.x, b0.y, b0.z, b0.w, b1.x, b1.y, b1.z, b1.w};
#pragma unroll
            for (int i = 0; i < 4; i++)
#pragma unroll
                for (int j = 0; j < 8; j++) acc[i][j] = fmaf(a[i], b[j], acc[i][j]);
        }
        __syncthreads();
    }

#pragma unroll
    for (int i = 0; i < 4; i++) {
        int d = d0 + ty * 4 + i;
        float bias = b_in[d];
        u32 pk[4];
#pragma unroll
        for (int j = 0; j < 4; j++) {
            u16 lo = f2bf(acc[i][2 * j] + bias);
            u16 hi = f2bf(acc[i][2 * j + 1] + bias);
            pk[j] = (u32)lo | ((u32)hi << 16);
        }
        uint4 u4; u4.x = pk[0]; u4.y = pk[1]; u4.z = pk[2]; u4.w = pk[3];
        *(uint4*)(qkv + (size_t)(n * D3 + d) * TV + p0 + tx * 8) = u4;
    }
}

// ---------------------------------------------------------------------------
// Kernel 2: scores. att[b=(n,s)][t][q] = tanh( sum_{c,v} Q[c,t,v]*K[c,q,v] / 1600 )
// K-loop chunked by whole c: per c the [t][v] slab is CONTIGUOUS in qkv layout.
// Tile: 128t x 64q, thread 8x4, v padded 25->28 (zeros) for float4 LDS reads.
// ---------------------------------------------------------------------------
__global__ __launch_bounds__(256) void k_scores(const u16* __restrict__ qkv,
                                                float* __restrict__ att) {
    const int b = blockIdx.z;
    const int n = b / 3, s = b % 3;
    const int t0 = blockIdx.y * 128, q0 = blockIdx.x * 64;
    const int tx = threadIdx.x, ty = threadIdx.y, tid = ty * 16 + tx;

    __shared__ float Qs[128][28];
    __shared__ float Ks[64][28];

    // zero the v-pad columns (25..27) once; chunk loads never touch them
    for (int l = tid; l < 576; l += 256) {
        int row = l / 3, v = 25 + l % 3;
        if (row < 128) Qs[row][v] = 0.f; else Ks[row - 128][v] = 0.f;
    }

    float acc[8][4];
#pragma unroll
    for (int i = 0; i < 8; i++)
#pragma unroll
        for (int j = 0; j < 4; j++) acc[i][j] = 0.f;

    const u16* qbase = qkv + (size_t)(n * D3 + s * 64) * TV;
    const u16* kbase = qkv + (size_t)(n * D3 + (3 + s) * 64) * TV;

    for (int c = 0; c < 64; c++) {
        const u32* qsrc = (const u32*)(qbase + (size_t)c * TV + t0 * 25);
#pragma unroll
        for (int r = 0; r < 7; r++) {
            int l = tid + 256 * r;
            if (l < 1600) {
                u32 w = qsrc[l];
                int e = 2 * l;       int tt = e / 25,  vv = e - tt * 25;
                int e1 = e + 1;      int tt1 = e1 / 25, vv1 = e1 - tt1 * 25;
                Qs[tt][vv]   = bf2f(w & 0xFFFFu);
                Qs[tt1][vv1] = bf2f(w >> 16);
            }
        }
        const u32* ksrc = (const u32*)(kbase + (size_t)c * TV + q0 * 25);
#pragma unroll
        for (int r = 0; r < 4; r++) {
            int l = tid + 256 * r;
            if (l < 800) {
                u32 w = ksrc[l];
                int e = 2 * l;       int qq = e / 25,  vv = e - qq * 25;
                int e1 = e + 1;      int qq1 = e1 / 25, vv1 = e1 - qq1 * 25;
                Ks[qq][vv]   = bf2f(w & 0xFFFFu);
                Ks[qq1][vv1] = bf2f(w >> 16);
            }
        }
        __syncthreads();
#pragma unroll
        for (int v4 = 0; v4 < 7; v4++) {
            float4 a4[8], b4[4];
#pragma unroll
            for (int i = 0; i < 8; i++) a4[i] = *(const float4*)&Qs[ty * 8 + i][v4 * 4];
#pragma unroll
            for (int j = 0; j < 4; j++) b4[j] = *(const float4*)&Ks[tx * 4 + j][v4 * 4];
#pragma unroll
            for (int i = 0; i < 8; i++)
#pragma unroll
                for (int j = 0; j < 4; j++) {
                    acc[i][j] = fmaf(a4[i].x, b4[j].x, acc[i][j]);
                    acc[i][j] = fmaf(a4[i].y, b4[j].y, acc[i][j]);
                    acc[i][j] = fmaf(a4[i].z, b4[j].z, acc[i][j]);
                    acc[i][j] = fmaf(a4[i].w, b4[j].w, acc[i][j]);
                }
        }
        __syncthreads();
    }

    const float sc = 1.0f / 1600.0f;
    float* ab = att + (size_t)b * 256 * 256;
#pragma unroll
    for (int i = 0; i < 8; i++) {
        int t = t0 + ty * 8 + i;
        float4 o;
        o.x = tanhf(acc[i][0] * sc);
        o.y = tanhf(acc[i][1] * sc);
        o.z = tanhf(acc[i][2] * sc);
        o.w = tanhf(acc[i][3] * sc);
        *(float4*)(ab + (size_t)t * 256 + q0 + tx * 4) = o;
    }
}

// ---------------------------------------------------------------------------
// Kernel 3: y[n, s*64+c, t, v] = sum_q att[b][t][q] * V[c][q][v]
// Per block: one (n,s), 64 t x 8 c x 25 v.  q chunked by 16.
// V slab per c is contiguous (400 elems per q-chunk). Thread: 2 t rows, 1 c.
// ---------------------------------------------------------------------------
__global__ __launch_bounds__(256) void k_av(const u16* __restrict__ qkv,
                                            const float* __restrict__ att,
                                            u16* __restrict__ y) {
    const int b = blockIdx.z;
    const int n = b / 3, s = b % 3;
    const int t0 = blockIdx.x * 64, c0 = blockIdx.y * 8;
    const int tid = threadIdx.x;
    const int tt0 = tid & 31, cc = tid >> 5;

    __shared__ float As[64][17];       // [t][q] pad 17
    __shared__ float Vs[8][16][28];    // [c][q][v pad 28]

    // zero v-pads
    for (int l = tid; l < 384; l += 256) {
        int c_ = l / 48; int rem = l % 48;
        Vs[c_][rem / 3][25 + rem % 3] = 0.f;
    }

    float4 acc0[7], acc1[7];
#pragma unroll
    for (int v4 = 0; v4 < 7; v4++) {
        acc0[v4] = make_float4(0.f, 0.f, 0.f, 0.f);
        acc1[v4] = make_float4(0.f, 0.f, 0.f, 0.f);
    }

    const u16* vbase = qkv + (size_t)(n * D3 + (6 + s) * 64 + c0) * TV;
    const float* ab = att + (size_t)b * 65536 + (size_t)t0 * 256;

    for (int q0 = 0; q0 < 256; q0 += 16) {
        // att tile 64t x 16q
#pragma unroll
        for (int r = 0; r < 4; r++) {
            int l = tid + 256 * r;
            int qq = l & 15, tt = l >> 4;
            As[tt][qq] = ab[tt * 256 + q0 + qq];
        }
        // V tile 8c x 16q x 25v  (contiguous 400-elem run per c)
#pragma unroll
        for (int r = 0; r < 7; r++) {
            int l = tid + 256 * r;
            if (l < 1600) {
                int c_ = l / 200; int rem2 = l - c_ * 200;
                u32 w = *(const u32*)(vbase + (size_t)c_ * TV + q0 * 25 + rem2 * 2);
                int e = 2 * rem2;  int qq = e / 25,  vv = e - qq * 25;
                int e1 = e + 1;    int qq1 = e1 / 25, vv1 = e1 - qq1 * 25;
                Vs[c_][qq][vv]   = bf2f(w & 0xFFFFu);
                Vs[c_][qq1][vv1] = bf2f(w >> 16);
            }
        }
        __syncthreads();
#pragma unroll
        for (int qq = 0; qq < 16; qq++) {
            float a0 = As[tt0][qq];
            float a1 = As[tt0 + 32][qq];
#pragma unroll
            for (int v4 = 0; v4 < 7; v4++) {
                float4 f = *(const float4*)&Vs[cc][qq][v4 * 4];
                acc0[v4].x = fmaf(a0, f.x, acc0[v4].x);
                acc0[v4].y = fmaf(a0, f.y, acc0[v4].y);
                acc0[v4].z = fmaf(a0, f.z, acc0[v4].z);
                acc0[v4].w = fmaf(a0, f.w, acc0[v4].w);
                acc1[v4].x = fmaf(a1, f.x, acc1[v4].x);
                acc1[v4].y = fmaf(a1, f.y, acc1[v4].y);
                acc1[v4].z = fmaf(a1, f.z, acc1[v4].z);
                acc1[v4].w = fmaf(a1, f.w, acc1[v4].w);
            }
        }
        __syncthreads();
    }

    const int crow = s * 64 + c0 + cc;
    u16* y0 = y + ((size_t)(n * NCH + crow) * 256 + (t0 + tt0)) * 25;
    u16* y1 = y0 + 32 * 25;
    const float* a0f = (const float*)acc0;
    const float* a1f = (const float*)acc1;
#pragma unroll
    for (int v = 0; v < 25; v++) {
        y0[v] = f2bf(a0f[v]);
        y1[v] = f2bf(a1f[v]);
    }
}

// ---------------------------------------------------------------------------
// Kernel 4: FF 1x1-conv + BN + residual + LeakyReLU(0.1)
// out[n,d,p] = act( x[n,d,p] + BN( sum_c y[n,c,p]*w_ff[d,c] + b_ff[d] ) )
// ---------------------------------------------------------------------------
__global__ __launch_bounds__(256) void k_ff(const u16* __restrict__ y,
                                            const float* __restrict__ x,
                                            const float* __restrict__ w_ff,
                                            const float* __restrict__ b_ff,
                                            const float* __restrict__ gamma,
                                            const float* __restrict__ beta,
                                            const float* __restrict__ mean,
                                            const float* __restrict__ var,
                                            float* __restrict__ out) {
    const int n = blockIdx.z, d0 = blockIdx.y * 64, p0 = blockIdx.x * 128;
    const int tx = threadIdx.x, ty = threadIdx.y, tid = ty * 16 + tx;

    __shared__ float Ws[16][68];
    __shared__ float Ys[16][128];

    float acc[4][8];
#pragma unroll
    for (int i = 0; i < 4; i++)
#pragma unroll
        for (int j = 0; j < 8; j++) acc[i][j] = 0.f;

    const u16* yn = y + (size_t)n * NCH * TV;

    for (int c0 = 0; c0 < 192; c0 += 16) {
#pragma unroll
        for (int r = 0; r < 4; r++) {
            int l = tid + 256 * r;
            int kk = l & 15, dd = l >> 4;
            Ws[kk][dd] = w_ff[(size_t)(d0 + dd) * 192 + c0 + kk];
        }
#pragma unroll
        for (int r = 0; r < 4; r++) {
            int l = tid + 256 * r;
            int pp2 = l & 63, kk = l >> 6;
            u32 w = *(const u32*)(yn + (size_t)(c0 + kk) * TV + p0 + pp2 * 2);
            Ys[kk][pp2 * 2]     = bf2f(w & 0xFFFFu);
            Ys[kk][pp2 * 2 + 1] = bf2f(w >> 16);
        }
        __syncthreads();
#pragma unroll
        for (int kk = 0; kk < 16; kk++) {
            float4 a4 = *(const float4*)&Ws[kk][ty * 4];
            float4 b0 = *(const float4*)&Ys[kk][tx * 8];
            float4 b1 = *(const float4*)&Ys[kk][tx * 8 + 4];
            float a[4] = {a4.x, a4.y, a4.z, a4.w};
            float bb[8] = {b0.x, b0.y, b0.z, b0.w, b1.x, b1.y, b1.z, b1.w};
#pragma unroll
            for (int i = 0; i < 4; i++)
#pragma unroll
                for (int j = 0; j < 8; j++) acc[i][j] = fmaf(a[i], bb[j], acc[i][j]);
        }
        __syncthreads();
    }

    const float* xn = x + (size_t)n * NCH * TV;
#pragma unroll
    for (int i = 0; i < 4; i++) {
        int d = d0 + ty * 4 + i;
        float inv = gamma[d] * rsqrtf(var[d] + 1e-5f);
        float bias = b_ff[d], mu = mean[d], bt = beta[d];
        float xv[8];
        float4 x0 = *(const float4*)(xn + (size_t)d * TV + p0 + tx * 8);
        float4 x1 = *(const float4*)(xn + (size_t)d * TV + p0 + tx * 8 + 4);
        xv[0] = x0.x; xv[1] = x0.y; xv[2] = x0.z; xv[3] = x0.w;
        xv[4] = x1.x; xv[5] = x1.y; xv[6] = x1.z; xv[7] = x1.w;
        float o[8];
#pragma unroll
        for (int j = 0; j < 8; j++) {
            float vv = acc[i][j] + bias;
            vv = (vv - mu) * inv + bt;
            float z = xv[j] + vv;
            o[j] = (z >= 0.f) ? z : 0.1f * z;
        }
        float4 o0, o1;
        o0.x = o[0]; o0.y = o[1]; o0.z = o[2]; o0.w = o[3];
        o1.x = o[4]; o1.y = o[5]; o1.z = o[6]; o1.w = o[7];
        float* op = out + (size_t)(n * NCH + d) * TV + p0 + tx * 8;
        *(float4*)op = o0;
        *(float4*)(op + 4) = o1;
    }
}

// ---------------------------------------------------------------------------
extern "C" void kernel_launch(void* const* d_in, const int* in_sizes, int n_in,
                              void* d_out, int out_size, void* d_ws, size_t ws_size,
                              hipStream_t stream) {
    const float* x     = (const float*)d_in[0];
    const float* w_in  = (const float*)d_in[1];
    const float* b_in  = (const float*)d_in[2];
    const float* w_ff  = (const float*)d_in[3];
    const float* b_ff  = (const float*)d_in[4];
    const float* gamma = (const float*)d_in[5];
    const float* beta  = (const float*)d_in[6];
    const float* mean  = (const float*)d_in[7];
    const float* var   = (const float*)d_in[8];

    // workspace layout (bytes): qkv bf16 [0, 235929600) | att f32 [.., 261095424) | y bf16 [.., 339738624)
    u16*   qkv = (u16*)d_ws;
    float* att = (float*)((char*)d_ws + 235929600ull);
    u16*   yb  = (u16*)((char*)d_ws + 261095424ull);
    float* out = (float*)d_out;

    k_qkv   <<<dim3(50, 9, 32), dim3(16, 16), 0, stream>>>(x, w_in, b_in, qkv);
    k_scores<<<dim3(4, 2, 96),  dim3(16, 16), 0, stream>>>(qkv, att);
    k_av    <<<dim3(4, 8, 96),  dim3(256),    0, stream>>>(qkv, att, yb);
    k_ff    <<<dim3(50, 3, 32), dim3(16, 16), 0, stream>>>(yb, x, w_ff, b_ff, gamma, beta, mean, var, out);
}

// Round 2
// 1424.707 us; speedup vs baseline: 1.5269x; 1.5269x over previous
//
#include <hip/hip_runtime.h>

// N=32, C=192, T=256, V=25, S=3, mid=64
#define TV 6400
#define NCH 192
#define D3 576

typedef unsigned short u16;
typedef unsigned int   u32;

typedef __attribute__((ext_vector_type(8))) short bf16x8;
typedef __attribute__((ext_vector_type(4))) float f32x4;

__device__ __forceinline__ float bf2f(u32 h) { return __uint_as_float(h << 16); }
__device__ __forceinline__ u16 f2bf(float f) {
    u32 u = __float_as_uint(f);
    return (u16)((u + 0x7FFFu + ((u >> 16) & 1u)) >> 16);
}

// ---------------------------------------------------------------------------
// Kernel 1 (unchanged): QKV projection, fp32 vector GEMM, bf16 out [n][d][t][v]
// ---------------------------------------------------------------------------
__global__ __launch_bounds__(256) void k_qkv(const float* __restrict__ x,
                                             const float* __restrict__ w_in,
                                             const float* __restrict__ b_in,
                                             u16* __restrict__ qkv) {
    const int n = blockIdx.z, d0 = blockIdx.y * 64, p0 = blockIdx.x * 128;
    const int tx = threadIdx.x, ty = threadIdx.y, tid = ty * 16 + tx;

    __shared__ float Ws[16][68];
    __shared__ float Xs[16][128];

    float acc[4][8];
#pragma unroll
    for (int i = 0; i < 4; i++)
#pragma unroll
        for (int j = 0; j < 8; j++) acc[i][j] = 0.f;

    const float* xn = x + (size_t)n * NCH * TV;

    for (int c0 = 0; c0 < 192; c0 += 16) {
#pragma unroll
        for (int r = 0; r < 4; r++) {
            int l = tid + 256 * r;
            int kk = l & 15, dd = l >> 4;
            Ws[kk][dd] = w_in[(size_t)(d0 + dd) * 192 + c0 + kk];
        }
#pragma unroll
        for (int r = 0; r < 2; r++) {
            int l = tid + 256 * r;
            int pp4 = l & 31, kk = l >> 5;
            float4 v = *(const float4*)(xn + (size_t)(c0 + kk) * TV + p0 + pp4 * 4);
            *(float4*)&Xs[kk][pp4 * 4] = v;
        }
        __syncthreads();
#pragma unroll
        for (int kk = 0; kk < 16; kk++) {
            float4 a4 = *(const float4*)&Ws[kk][ty * 4];
            float4 b0 = *(const float4*)&Xs[kk][tx * 8];
            float4 b1 = *(const float4*)&Xs[kk][tx * 8 + 4];
            float a[4] = {a4.x, a4.y, a4.z, a4.w};
            float b[8] = {b0.x, b0.y, b0.z, b0.w, b1.x, b1.y, b1.z, b1.w};
#pragma unroll
            for (int i = 0; i < 4; i++)
#pragma unroll
                for (int j = 0; j < 8; j++) acc[i][j] = fmaf(a[i], b[j], acc[i][j]);
        }
        __syncthreads();
    }

#pragma unroll
    for (int i = 0; i < 4; i++) {
        int d = d0 + ty * 4 + i;
        float bias = b_in[d];
        u32 pk[4];
#pragma unroll
        for (int j = 0; j < 4; j++) {
            u16 lo = f2bf(acc[i][2 * j] + bias);
            u16 hi = f2bf(acc[i][2 * j + 1] + bias);
            pk[j] = (u32)lo | ((u32)hi << 16);
        }
        uint4 u4; u4.x = pk[0]; u4.y = pk[1]; u4.z = pk[2]; u4.w = pk[3];
        *(uint4*)(qkv + (size_t)(n * D3 + d) * TV + p0 + tx * 8) = u4;
    }
}

// ---------------------------------------------------------------------------
// Kernel 2: transpose Q,K parts -> qt/kt [b=(n,s)][t][k=c*25+v], K=1600
// Block: (t-chunk 16, part*3+s, n). LDS staged, both sides coalesced.
// ---------------------------------------------------------------------------
__global__ __launch_bounds__(256) void k_tr(const u16* __restrict__ qkv,
                                            u16* __restrict__ qt,
                                            u16* __restrict__ kt) {
    const int t0 = blockIdx.x * 16;
    const int ps = blockIdx.y;
    const int part = ps / 3, s = ps % 3;
    const int n = blockIdx.z;
    const int tid = threadIdx.x;

    __shared__ u32 tl[64 * 201];   // [c][200 u32] + 1 u32 pad per row

    const u16* src = qkv + ((size_t)n * D3 + part * 192 + s * 64) * TV;
#pragma unroll
    for (int r = 0; r < 50; r++) {
        int idx = tid + 256 * r;
        int c = idx / 200, off = idx - 200 * c;
        tl[c * 201 + off] = *(const u32*)(src + (size_t)c * TV + t0 * 25 + off * 2);
    }
    __syncthreads();
    const u16* tl16 = (const u16*)tl;
    u16* dst = (part == 0 ? qt : kt) + ((size_t)(n * 3 + s) * 256 + t0) * 1600;
#pragma unroll
    for (int r = 0; r < 50; r++) {
        int idx = tid + 256 * r;
        int ti = idx / 800; int k2 = idx - 800 * ti;
        int e0 = 2 * k2;  int c0 = e0 / 25, v0 = e0 - 25 * c0;
        int e1 = e0 + 1;  int c1 = e1 / 25, v1 = e1 - 25 * c1;
        u32 lo = tl16[c0 * 402 + ti * 25 + v0];
        u32 hi = tl16[c1 * 402 + ti * 25 + v1];
        *(u32*)(dst + (size_t)ti * 1600 + e0) = lo | (hi << 16);
    }
}

// ---------------------------------------------------------------------------
// Kernel 3: scores MFMA. att[b][t][q] = tanh(sum_k qt[b][t][k]*kt[b][q][k]/1600)
// Block 128t x 64q, 4 waves (2m x 2n), K chunks of 64. XOR-swizzled LDS.
// ---------------------------------------------------------------------------
__global__ __launch_bounds__(256) void k_scores(const u16* __restrict__ qt,
                                                const u16* __restrict__ kt,
                                                u16* __restrict__ att) {
    const int b = blockIdx.z, t0 = blockIdx.y * 128, q0 = blockIdx.x * 64;
    const int tid = threadIdx.x;
    const int wid = tid >> 6, lane = tid & 63;
    const int wm = wid & 1, wn = wid >> 1;
    const int ml = lane & 15, kq = lane >> 4;

    __shared__ __align__(16) char As[128 * 128];  // [t][64k] bf16, swizzled
    __shared__ __align__(16) char Bs[64 * 128];   // [q][64k]

    f32x4 acc[4][2];
#pragma unroll
    for (int i = 0; i < 4; i++)
#pragma unroll
        for (int j = 0; j < 2; j++)
#pragma unroll
            for (int r = 0; r < 4; r++) acc[i][j][r] = 0.f;

    const u16* qb = qt + (size_t)b * 256 * 1600;
    const u16* kb = kt + (size_t)b * 256 * 1600;

    for (int kc = 0; kc < 1600; kc += 64) {
#pragma unroll
        for (int r = 0; r < 4; r++) {
            int idx = tid + 256 * r;
            int row = idx >> 3, g = idx & 7;
            uint4 v = *(const uint4*)(qb + (size_t)(t0 + row) * 1600 + kc + g * 8);
            *(uint4*)(As + row * 128 + (((g ^ row) & 7) << 4)) = v;
        }
#pragma unroll
        for (int r = 0; r < 2; r++) {
            int idx = tid + 256 * r;
            int row = idx >> 3, g = idx & 7;
            uint4 v = *(const uint4*)(kb + (size_t)(q0 + row) * 1600 + kc + g * 8);
            *(uint4*)(Bs + row * 128 + (((g ^ row) & 7) << 4)) = v;
        }
        __syncthreads();
#pragma unroll
        for (int ks = 0; ks < 2; ks++) {
            int gb = ks * 4 + kq;
            bf16x8 a[4], bb[2];
#pragma unroll
            for (int mt = 0; mt < 4; mt++) {
                int row = wm * 64 + mt * 16 + ml;
                a[mt] = *(const bf16x8*)(As + row * 128 + (((gb ^ row) & 7) << 4));
            }
#pragma unroll
            for (int nt = 0; nt < 2; nt++) {
                int row = wn * 32 + nt * 16 + ml;
                bb[nt] = *(const bf16x8*)(Bs + row * 128 + (((gb ^ row) & 7) << 4));
            }
#pragma unroll
            for (int mt = 0; mt < 4; mt++)
#pragma unroll
                for (int nt = 0; nt < 2; nt++)
                    acc[mt][nt] = __builtin_amdgcn_mfma_f32_16x16x32_bf16(a[mt], bb[nt], acc[mt][nt], 0, 0, 0);
        }
        __syncthreads();
    }

    const float sc = 1.0f / 1600.0f;
    u16* ab = att + (size_t)b * 65536;
#pragma unroll
    for (int mt = 0; mt < 4; mt++)
#pragma unroll
        for (int nt = 0; nt < 2; nt++) {
            int q = q0 + wn * 32 + nt * 16 + ml;
#pragma unroll
            for (int r = 0; r < 4; r++) {
                int t = t0 + wm * 64 + mt * 16 + kq * 4 + r;
                ab[(size_t)t * 256 + q] = f2bf(tanhf(acc[mt][nt][r] * sc));
            }
        }
}

// ---------------------------------------------------------------------------
// Kernel 4: AV MFMA. y_t[n][p=(t*25+v)][cg=s*64+c] = sum_q att[b][t][q]*V[c][q][v]
// Block: one (b, t-tile 128, v0). N = 64 c's. V transposed into LDS via u16 gather.
// ---------------------------------------------------------------------------
__global__ __launch_bounds__(256) void k_av(const u16* __restrict__ qkv,
                                            const u16* __restrict__ att,
                                            u16* __restrict__ y_t) {
    const int b = blockIdx.z, t0 = blockIdx.y * 128, v0 = blockIdx.x;
    const int n = b / 3, s = b % 3;
    const int tid = threadIdx.x;
    const int wid = tid >> 6, lane = tid & 63;
    const int wm = wid & 1, wn = wid >> 1;
    const int ml = lane & 15, kq = lane >> 4;

    __shared__ __align__(16) char As[128 * 128];  // [t][64q] bf16
    __shared__ __align__(16) char Bs[64 * 128];   // [c][64q] bf16 (V^T slice at v0)

    f32x4 acc[4][2];
#pragma unroll
    for (int i = 0; i < 4; i++)
#pragma unroll
        for (int j = 0; j < 2; j++)
#pragma unroll
            for (int r = 0; r < 4; r++) acc[i][j][r] = 0.f;

    const u16* ab = att + (size_t)b * 65536;
    const int cgath = tid >> 2, qg = tid & 3;
    const u16* vsrc = qkv + ((size_t)n * D3 + 384 + s * 64 + cgath) * TV + v0;

    for (int kc = 0; kc < 256; kc += 64) {
#pragma unroll
        for (int r = 0; r < 4; r++) {
            int idx = tid + 256 * r;
            int row = idx >> 3, g = idx & 7;
            uint4 v = *(const uint4*)(ab + (size_t)(t0 + row) * 256 + kc + g * 8);
            *(uint4*)(As + row * 128 + (((g ^ row) & 7) << 4)) = v;
        }
        // V gather: thread covers (c=cgath, 16 q's)
#pragma unroll
        for (int i = 0; i < 16; i++) {
            int ql = qg * 16 + i;
            u16 val = vsrc[(size_t)(kc + ql) * 25];
            int g = ql >> 3;
            *(u16*)(Bs + cgath * 128 + (((g ^ cgath) & 7) << 4) + (ql & 7) * 2) = val;
        }
        __syncthreads();
#pragma unroll
        for (int ks = 0; ks < 2; ks++) {
            int gb = ks * 4 + kq;
            bf16x8 a[4], bb[2];
#pragma unroll
            for (int mt = 0; mt < 4; mt++) {
                int row = wm * 64 + mt * 16 + ml;
                a[mt] = *(const bf16x8*)(As + row * 128 + (((gb ^ row) & 7) << 4));
            }
#pragma unroll
            for (int nt = 0; nt < 2; nt++) {
                int row = wn * 32 + nt * 16 + ml;
                bb[nt] = *(const bf16x8*)(Bs + row * 128 + (((gb ^ row) & 7) << 4));
            }
#pragma unroll
            for (int mt = 0; mt < 4; mt++)
#pragma unroll
                for (int nt = 0; nt < 2; nt++)
                    acc[mt][nt] = __builtin_amdgcn_mfma_f32_16x16x32_bf16(a[mt], bb[nt], acc[mt][nt], 0, 0, 0);
        }
        __syncthreads();
    }

#pragma unroll
    for (int mt = 0; mt < 4; mt++)
#pragma unroll
        for (int nt = 0; nt < 2; nt++) {
            int cg = s * 64 + wn * 32 + nt * 16 + ml;
#pragma unroll
            for (int r = 0; r < 4; r++) {
                int t = t0 + wm * 64 + mt * 16 + kq * 4 + r;
                y_t[((size_t)n * TV + t * 25 + v0) * 192 + cg] = f2bf(acc[mt][nt][r]);
            }
        }
}

// ---------------------------------------------------------------------------
// Kernel 5: FF MFMA + BN + residual + LeakyReLU.
// out[n,d,p] = act(x + BN(sum_c y_t[n][p][c]*w_ff[d][c] + b_ff[d]))
// Block: 64d x 128p, K=192 in 3 chunks of 64. A=w_ff (cast bf16), B=y_t rows.
// ---------------------------------------------------------------------------
__global__ __launch_bounds__(256) void k_ff(const u16* __restrict__ y_t,
                                            const float* __restrict__ x,
                                            const float* __restrict__ w_ff,
                                            const float* __restrict__ b_ff,
                                            const float* __restrict__ gamma,
                                            const float* __restrict__ beta,
                                            const float* __restrict__ mean,
                                            const float* __restrict__ var,
                                            float* __restrict__ out) {
    const int n = blockIdx.z, d0 = blockIdx.y * 64, p0 = blockIdx.x * 128;
    const int tid = threadIdx.x;
    const int wid = tid >> 6, lane = tid & 63;
    const int wn = wid;                 // 4 waves along N(p); M=64 shared
    const int ml = lane & 15, kq = lane >> 4;

    __shared__ __align__(16) char Aw[64 * 128];   // [d][64c] bf16
    __shared__ __align__(16) char By[128 * 128];  // [p][64c] bf16

    f32x4 acc[4][2];
#pragma unroll
    for (int i = 0; i < 4; i++)
#pragma unroll
        for (int j = 0; j < 2; j++)
#pragma unroll
            for (int r = 0; r < 4; r++) acc[i][j][r] = 0.f;

    for (int kc = 0; kc < 192; kc += 64) {
        // A: w_ff fp32 -> bf16, 64x64
#pragma unroll
        for (int r = 0; r < 8; r++) {
            int idx = tid + 256 * r;
            int row = idx >> 5, kp = idx & 31;
            int k = kp * 2;
            float2 f = *(const float2*)(w_ff + (size_t)(d0 + row) * 192 + kc + k);
            u32 pk = (u32)f2bf(f.x) | ((u32)f2bf(f.y) << 16);
            int g = k >> 3, sub = k & 7;
            *(u32*)(Aw + row * 128 + (((g ^ row) & 7) << 4) + sub * 2) = pk;
        }
        // B: y_t rows (contiguous c)
#pragma unroll
        for (int r = 0; r < 4; r++) {
            int idx = tid + 256 * r;
            int row = idx >> 3, g = idx & 7;
            uint4 v = *(const uint4*)(y_t + ((size_t)n * TV + p0 + row) * 192 + kc + g * 8);
            *(uint4*)(By + row * 128 + (((g ^ row) & 7) << 4)) = v;
        }
        __syncthreads();
#pragma unroll
        for (int ks = 0; ks < 2; ks++) {
            int gb = ks * 4 + kq;
            bf16x8 a[4], bb[2];
#pragma unroll
            for (int mt = 0; mt < 4; mt++) {
                int row = mt * 16 + ml;
                a[mt] = *(const bf16x8*)(Aw + row * 128 + (((gb ^ row) & 7) << 4));
            }
#pragma unroll
            for (int nt = 0; nt < 2; nt++) {
                int row = wn * 32 + nt * 16 + ml;
                bb[nt] = *(const bf16x8*)(By + row * 128 + (((gb ^ row) & 7) << 4));
            }
#pragma unroll
            for (int mt = 0; mt < 4; mt++)
#pragma unroll
                for (int nt = 0; nt < 2; nt++)
                    acc[mt][nt] = __builtin_amdgcn_mfma_f32_16x16x32_bf16(a[mt], bb[nt], acc[mt][nt], 0, 0, 0);
        }
        __syncthreads();
    }

#pragma unroll
    for (int mt = 0; mt < 4; mt++)
#pragma unroll
        for (int r = 0; r < 4; r++) {
            int d = d0 + mt * 16 + kq * 4 + r;
            float inv = gamma[d] * rsqrtf(var[d] + 1e-5f);
            float bias = b_ff[d], mu = mean[d], bt = beta[d];
#pragma unroll
            for (int nt = 0; nt < 2; nt++) {
                int p = p0 + wn * 32 + nt * 16 + ml;
                size_t xi = ((size_t)n * NCH + d) * TV + p;
                float v = acc[mt][nt][r] + bias;
                v = (v - mu) * inv + bt;
                float z = x[xi] + v;
                out[xi] = (z >= 0.f) ? z : 0.1f * z;
            }
        }
}

// ---------------------------------------------------------------------------
extern "C" void kernel_launch(void* const* d_in, const int* in_sizes, int n_in,
                              void* d_out, int out_size, void* d_ws, size_t ws_size,
                              hipStream_t stream) {
    const float* x     = (const float*)d_in[0];
    const float* w_in  = (const float*)d_in[1];
    const float* b_in  = (const float*)d_in[2];
    const float* w_ff  = (const float*)d_in[3];
    const float* b_ff  = (const float*)d_in[4];
    const float* gamma = (const float*)d_in[5];
    const float* beta  = (const float*)d_in[6];
    const float* mean  = (const float*)d_in[7];
    const float* var   = (const float*)d_in[8];

    // d_ws layout: qkv bf16 [0, 235929600) | att bf16 [.., 248512512) | y_t bf16 [.., 327155712)
    u16* qkv = (u16*)d_ws;
    u16* att = (u16*)((char*)d_ws + 235929600ull);
    u16* y_t = (u16*)((char*)d_ws + 248512512ull);
    // d_out doubles as scratch for qt/kt (157.3 MB, exact fit); k_ff overwrites it last.
    u16* qt = (u16*)d_out;
    u16* kt = qt + 39321600ull;
    float* out = (float*)d_out;

    k_qkv   <<<dim3(50, 9, 32), dim3(16, 16), 0, stream>>>(x, w_in, b_in, qkv);
    k_tr    <<<dim3(16, 6, 32), dim3(256),    0, stream>>>(qkv, qt, kt);
    k_scores<<<dim3(4, 2, 96),  dim3(256),    0, stream>>>(qt, kt, att);
    k_av    <<<dim3(25, 2, 96), dim3(256),    0, stream>>>(qkv, att, y_t);
    k_ff    <<<dim3(50, 3, 32), dim3(256),    0, stream>>>(y_t, x, w_ff, b_ff, gamma, beta, mean, var, out);
}

// Round 3
// 1006.760 us; speedup vs baseline: 2.1607x; 1.4151x over previous
//
#include <hip/hip_runtime.h>

// N=32, C=192, T=256, V=25, S=3, mid=64
#define TV 6400
#define NCH 192
#define D3 576

typedef unsigned short u16;
typedef unsigned int   u32;

typedef __attribute__((ext_vector_type(8))) short bf16x8;
typedef __attribute__((ext_vector_type(4))) float f32x4;

__device__ __forceinline__ float bf2f(u32 h) { return __uint_as_float(h << 16); }
__device__ __forceinline__ u16 f2bf(float f) {
    u32 u = __float_as_uint(f);
    return (u16)((u + 0x7FFFu + ((u >> 16) & 1u)) >> 16);
}

// ---------------------------------------------------------------------------
// Kernel 0a: cast w_in (576x192) and w_ff (192x192) fp32 -> bf16, packed flat.
// ---------------------------------------------------------------------------
__global__ __launch_bounds__(256) void k_wcast(const float* __restrict__ w_in,
                                               const float* __restrict__ w_ff,
                                               u32* __restrict__ wb) {
    int i = blockIdx.x * 256 + threadIdx.x;   // < 73728
    float2 f;
    if (i < 55296) f = *(const float2*)(w_in + 2 * i);
    else           f = *(const float2*)(w_ff + 2 * (i - 55296));
    wb[i] = (u32)f2bf(f.x) | ((u32)f2bf(f.y) << 16);
}

// ---------------------------------------------------------------------------
// Kernel 0b: transpose x [n][c][p] fp32 -> x_t [n][p][c] bf16.
// ---------------------------------------------------------------------------
__global__ __launch_bounds__(256) void k_trx(const float* __restrict__ x,
                                             u16* __restrict__ x_t) {
    const int p0 = blockIdx.x * 128, c0 = blockIdx.y * 64, n = blockIdx.z;
    const int tid = threadIdx.x;
    __shared__ float L[64][129];
    const float* xn = x + ((size_t)n * NCH + c0) * TV + p0;
#pragma unroll
    for (int r = 0; r < 8; ++r) {
        int idx = tid + 256 * r;
        int c = idx >> 5, p4 = idx & 31;
        float4 v = *(const float4*)(xn + (size_t)c * TV + p4 * 4);
        *(float4*)&L[c][p4 * 4] = v;
    }
    __syncthreads();
    const int row = tid >> 1, ch = (tid & 1) * 32;
    u16* dst = x_t + ((size_t)n * TV + p0 + row) * 192 + c0 + ch;
    u32 buf[16];
#pragma unroll
    for (int j = 0; j < 16; ++j) {
        float f0 = L[ch + 2 * j][row], f1 = L[ch + 2 * j + 1][row];
        buf[j] = (u32)f2bf(f0) | ((u32)f2bf(f1) << 16);
    }
#pragma unroll
    for (int q = 0; q < 4; ++q) {
        uint4 u; u.x = buf[q * 4]; u.y = buf[q * 4 + 1]; u.z = buf[q * 4 + 2]; u.w = buf[q * 4 + 3];
        *(uint4*)(dst + q * 8) = u;
    }
}

// ---------------------------------------------------------------------------
// Kernel 1: QKV projection via MFMA.
// qkv[n,d,p] = sum_c x_t[n][p][c] * w_in[d][c] + b_in[d]
// A = x_t (M=128 p), B = w_in bf16 (N = 64 d per d-tile, 9 tiles looped).
// Bs (x_t tile, all K=192) staged ONCE; As restaged per d-tile.
// ---------------------------------------------------------------------------
__global__ __launch_bounds__(256) void k_qkv(const u16* __restrict__ x_t,
                                             const u16* __restrict__ w_inb,
                                             const float* __restrict__ b_in,
                                             u16* __restrict__ qkv) {
    const int p0 = blockIdx.x * 128, n = blockIdx.y;
    const int tid = threadIdx.x;
    const int wid = tid >> 6, lane = tid & 63;
    const int wm = wid & 1, wn = wid >> 1;
    const int ml = lane & 15, kq = lane >> 4;

    __shared__ __align__(16) char Bs[128 * 384];  // x_t tile [p][192c] bf16, swizzled
    __shared__ __align__(16) char As[64 * 384];   // w tile [d][192c] bf16, swizzled

    // Stage Bs once (3072 uint4)
#pragma unroll
    for (int r = 0; r < 12; ++r) {
        int idx = tid + 256 * r;
        int row = idx / 24, g = idx - row * 24;
        uint4 v = *(const uint4*)(x_t + ((size_t)n * TV + p0 + row) * 192 + g * 8);
        *(uint4*)(Bs + row * 384 + (((g & ~7) | ((g ^ row) & 7)) << 4)) = v;
    }

    for (int dt = 0; dt < 9; ++dt) {
        // Stage As: w rows dt*64 .. +64, all 192 c (1536 uint4)
#pragma unroll
        for (int r = 0; r < 6; ++r) {
            int idx = tid + 256 * r;
            int row = idx / 24, g = idx - row * 24;
            uint4 v = *(const uint4*)(w_inb + (size_t)(dt * 64 + row) * 192 + g * 8);
            *(uint4*)(As + row * 384 + (((g & ~7) | ((g ^ row) & 7)) << 4)) = v;
        }
        __syncthreads();

        f32x4 acc[4][2];
#pragma unroll
        for (int i = 0; i < 4; i++)
#pragma unroll
            for (int j = 0; j < 2; j++)
#pragma unroll
                for (int r = 0; r < 4; r++) acc[i][j][r] = 0.f;

#pragma unroll
        for (int kk = 0; kk < 3; ++kk)
#pragma unroll
            for (int ks = 0; ks < 2; ++ks) {
                int g = kk * 8 + ks * 4 + kq;
                bf16x8 a[4], bb[2];
#pragma unroll
                for (int mt = 0; mt < 4; ++mt) {
                    int row = wm * 64 + mt * 16 + ml;
                    a[mt] = *(const bf16x8*)(Bs + row * 384 + (((g & ~7) | ((g ^ row) & 7)) << 4));
                }
#pragma unroll
                for (int nt = 0; nt < 2; ++nt) {
                    int row = wn * 32 + nt * 16 + ml;
                    bb[nt] = *(const bf16x8*)(As + row * 384 + (((g & ~7) | ((g ^ row) & 7)) << 4));
                }
#pragma unroll
                for (int mt = 0; mt < 4; ++mt)
#pragma unroll
                    for (int nt = 0; nt < 2; ++nt)
                        acc[mt][nt] = __builtin_amdgcn_mfma_f32_16x16x32_bf16(a[mt], bb[nt], acc[mt][nt], 0, 0, 0);
            }

        // Epilogue: col(lane&15)=d, rows(kq*4+r)=p -> 8B packed stores
#pragma unroll
        for (int nt = 0; nt < 2; ++nt) {
            int d = dt * 64 + wn * 32 + nt * 16 + ml;
            float bias = b_in[d];
#pragma unroll
            for (int mt = 0; mt < 4; ++mt) {
                int p = p0 + wm * 64 + mt * 16 + kq * 4;
                u32 w0 = (u32)f2bf(acc[mt][nt][0] + bias) | ((u32)f2bf(acc[mt][nt][1] + bias) << 16);
                u32 w1 = (u32)f2bf(acc[mt][nt][2] + bias) | ((u32)f2bf(acc[mt][nt][3] + bias) << 16);
                uint2 u; u.x = w0; u.y = w1;
                *(uint2*)(qkv + ((size_t)n * D3 + d) * TV + p) = u;
            }
        }
        __syncthreads();
    }
}

// ---------------------------------------------------------------------------
// Kernel 2: transpose Q,K parts -> qt/kt [b=(n,s)][t][k=c*25+v], K=1600
// ---------------------------------------------------------------------------
__global__ __launch_bounds__(256) void k_tr(const u16* __restrict__ qkv,
                                            u16* __restrict__ qt,
                                            u16* __restrict__ kt) {
    const int t0 = blockIdx.x * 16;
    const int ps = blockIdx.y;
    const int part = ps / 3, s = ps % 3;
    const int n = blockIdx.z;
    const int tid = threadIdx.x;

    __shared__ u32 tl[64 * 201];

    const u16* src = qkv + ((size_t)n * D3 + part * 192 + s * 64) * TV;
#pragma unroll
    for (int r = 0; r < 50; r++) {
        int idx = tid + 256 * r;
        int c = idx / 200, off = idx - 200 * c;
        tl[c * 201 + off] = *(const u32*)(src + (size_t)c * TV + t0 * 25 + off * 2);
    }
    __syncthreads();
    const u16* tl16 = (const u16*)tl;
    u16* dst = (part == 0 ? qt : kt) + ((size_t)(n * 3 + s) * 256 + t0) * 1600;
#pragma unroll
    for (int r = 0; r < 50; r++) {
        int idx = tid + 256 * r;
        int ti = idx / 800; int k2 = idx - 800 * ti;
        int e0 = 2 * k2;  int c0 = e0 / 25, v0 = e0 - 25 * c0;
        int e1 = e0 + 1;  int c1 = e1 / 25, v1 = e1 - 25 * c1;
        u32 lo = tl16[c0 * 402 + ti * 25 + v0];
        u32 hi = tl16[c1 * 402 + ti * 25 + v1];
        *(u32*)(dst + (size_t)ti * 1600 + e0) = lo | (hi << 16);
    }
}

// ---------------------------------------------------------------------------
// Kernel 3: scores MFMA. att[b][t][q] = tanh(sum_k qt[b][t][k]*kt[b][q][k]/1600)
// ---------------------------------------------------------------------------
__global__ __launch_bounds__(256) void k_scores(const u16* __restrict__ qt,
                                                const u16* __restrict__ kt,
                                                u16* __restrict__ att) {
    const int b = blockIdx.z, t0 = blockIdx.y * 128, q0 = blockIdx.x * 64;
    const int tid = threadIdx.x;
    const int wid = tid >> 6, lane = tid & 63;
    const int wm = wid & 1, wn = wid >> 1;
    const int ml = lane & 15, kq = lane >> 4;

    __shared__ __align__(16) char As[128 * 128];
    __shared__ __align__(16) char Bs[64 * 128];

    f32x4 acc[4][2];
#pragma unroll
    for (int i = 0; i < 4; i++)
#pragma unroll
        for (int j = 0; j < 2; j++)
#pragma unroll
            for (int r = 0; r < 4; r++) acc[i][j][r] = 0.f;

    const u16* qb = qt + (size_t)b * 256 * 1600;
    const u16* kb = kt + (size_t)b * 256 * 1600;

    for (int kc = 0; kc < 1600; kc += 64) {
#pragma unroll
        for (int r = 0; r < 4; r++) {
            int idx = tid + 256 * r;
            int row = idx >> 3, g = idx & 7;
            uint4 v = *(const uint4*)(qb + (size_t)(t0 + row) * 1600 + kc + g * 8);
            *(uint4*)(As + row * 128 + (((g ^ row) & 7) << 4)) = v;
        }
#pragma unroll
        for (int r = 0; r < 2; r++) {
            int idx = tid + 256 * r;
            int row = idx >> 3, g = idx & 7;
            uint4 v = *(const uint4*)(kb + (size_t)(q0 + row) * 1600 + kc + g * 8);
            *(uint4*)(Bs + row * 128 + (((g ^ row) & 7) << 4)) = v;
        }
        __syncthreads();
#pragma unroll
        for (int ks = 0; ks < 2; ks++) {
            int gb = ks * 4 + kq;
            bf16x8 a[4], bb[2];
#pragma unroll
            for (int mt = 0; mt < 4; mt++) {
                int row = wm * 64 + mt * 16 + ml;
                a[mt] = *(const bf16x8*)(As + row * 128 + (((gb ^ row) & 7) << 4));
            }
#pragma unroll
            for (int nt = 0; nt < 2; nt++) {
                int row = wn * 32 + nt * 16 + ml;
                bb[nt] = *(const bf16x8*)(Bs + row * 128 + (((gb ^ row) & 7) << 4));
            }
#pragma unroll
            for (int mt = 0; mt < 4; mt++)
#pragma unroll
                for (int nt = 0; nt < 2; nt++)
                    acc[mt][nt] = __builtin_amdgcn_mfma_f32_16x16x32_bf16(a[mt], bb[nt], acc[mt][nt], 0, 0, 0);
        }
        __syncthreads();
    }

    const float sc = 1.0f / 1600.0f;
    u16* ab = att + (size_t)b * 65536;
#pragma unroll
    for (int mt = 0; mt < 4; mt++)
#pragma unroll
        for (int nt = 0; nt < 2; nt++) {
            int q = q0 + wn * 32 + nt * 16 + ml;
#pragma unroll
            for (int r = 0; r < 4; r++) {
                int t = t0 + wm * 64 + mt * 16 + kq * 4 + r;
                ab[(size_t)t * 256 + q] = f2bf(tanhf(acc[mt][nt][r] * sc));
            }
        }
}

// ---------------------------------------------------------------------------
// Kernel 4: AV MFMA. y_t[n][p=(t*25+v)][cg] = sum_q att[b][t][q]*V[c][q][v]
// ---------------------------------------------------------------------------
__global__ __launch_bounds__(256) void k_av(const u16* __restrict__ qkv,
                                            const u16* __restrict__ att,
                                            u16* __restrict__ y_t) {
    const int b = blockIdx.z, t0 = blockIdx.y * 128, v0 = blockIdx.x;
    const int n = b / 3, s = b % 3;
    const int tid = threadIdx.x;
    const int wid = tid >> 6, lane = tid & 63;
    const int wm = wid & 1, wn = wid >> 1;
    const int ml = lane & 15, kq = lane >> 4;

    __shared__ __align__(16) char As[128 * 128];
    __shared__ __align__(16) char Bs[64 * 128];

    f32x4 acc[4][2];
#pragma unroll
    for (int i = 0; i < 4; i++)
#pragma unroll
        for (int j = 0; j < 2; j++)
#pragma unroll
            for (int r = 0; r < 4; r++) acc[i][j][r] = 0.f;

    const u16* ab = att + (size_t)b * 65536;
    const int cgath = tid >> 2, qg = tid & 3;
    const u16* vsrc = qkv + ((size_t)n * D3 + 384 + s * 64 + cgath) * TV + v0;

    for (int kc = 0; kc < 256; kc += 64) {
#pragma unroll
        for (int r = 0; r < 4; r++) {
            int idx = tid + 256 * r;
            int row = idx >> 3, g = idx & 7;
            uint4 v = *(const uint4*)(ab + (size_t)(t0 + row) * 256 + kc + g * 8);
            *(uint4*)(As + row * 128 + (((g ^ row) & 7) << 4)) = v;
        }
#pragma unroll
        for (int i = 0; i < 16; i++) {
            int ql = qg * 16 + i;
            u16 val = vsrc[(size_t)(kc + ql) * 25];
            int g = ql >> 3;
            *(u16*)(Bs + cgath * 128 + (((g ^ cgath) & 7) << 4) + (ql & 7) * 2) = val;
        }
        __syncthreads();
#pragma unroll
        for (int ks = 0; ks < 2; ks++) {
            int gb = ks * 4 + kq;
            bf16x8 a[4], bb[2];
#pragma unroll
            for (int mt = 0; mt < 4; mt++) {
                int row = wm * 64 + mt * 16 + ml;
                a[mt] = *(const bf16x8*)(As + row * 128 + (((gb ^ row) & 7) << 4));
            }
#pragma unroll
            for (int nt = 0; nt < 2; nt++) {
                int row = wn * 32 + nt * 16 + ml;
                bb[nt] = *(const bf16x8*)(Bs + row * 128 + (((gb ^ row) & 7) << 4));
            }
#pragma unroll
            for (int mt = 0; mt < 4; mt++)
#pragma unroll
                for (int nt = 0; nt < 2; nt++)
                    acc[mt][nt] = __builtin_amdgcn_mfma_f32_16x16x32_bf16(a[mt], bb[nt], acc[mt][nt], 0, 0, 0);
        }
        __syncthreads();
    }

#pragma unroll
    for (int mt = 0; mt < 4; mt++)
#pragma unroll
        for (int nt = 0; nt < 2; nt++) {
            int cg = s * 64 + wn * 32 + nt * 16 + ml;
#pragma unroll
            for (int r = 0; r < 4; r++) {
                int t = t0 + wm * 64 + mt * 16 + kq * 4 + r;
                y_t[((size_t)n * TV + t * 25 + v0) * 192 + cg] = f2bf(acc[mt][nt][r]);
            }
        }
}

// ---------------------------------------------------------------------------
// Kernel 5: FF MFMA + BN + residual + LeakyReLU.
// ---------------------------------------------------------------------------
__global__ __launch_bounds__(256) void k_ff(const u16* __restrict__ y_t,
                                            const float* __restrict__ x,
                                            const u16* __restrict__ w_ffb,
                                            const float* __restrict__ b_ff,
                                            const float* __restrict__ gamma,
                                            const float* __restrict__ beta,
                                            const float* __restrict__ mean,
                                            const float* __restrict__ var,
                                            float* __restrict__ out) {
    const int n = blockIdx.z, d0 = blockIdx.y * 64, p0 = blockIdx.x * 128;
    const int tid = threadIdx.x;
    const int wid = tid >> 6, lane = tid & 63;
    const int wn = wid;
    const int ml = lane & 15, kq = lane >> 4;

    __shared__ __align__(16) char Aw[64 * 128];
    __shared__ __align__(16) char By[128 * 128];

    f32x4 acc[4][2];
#pragma unroll
    for (int i = 0; i < 4; i++)
#pragma unroll
        for (int j = 0; j < 2; j++)
#pragma unroll
            for (int r = 0; r < 4; r++) acc[i][j][r] = 0.f;

    for (int kc = 0; kc < 192; kc += 64) {
#pragma unroll
        for (int r = 0; r < 2; r++) {
            int idx = tid + 256 * r;
            int row = idx >> 3, g = idx & 7;
            uint4 v = *(const uint4*)(w_ffb + (size_t)(d0 + row) * 192 + kc + g * 8);
            *(uint4*)(Aw + row * 128 + (((g ^ row) & 7) << 4)) = v;
        }
#pragma unroll
        for (int r = 0; r < 4; r++) {
            int idx = tid + 256 * r;
            int row = idx >> 3, g = idx & 7;
            uint4 v = *(const uint4*)(y_t + ((size_t)n * TV + p0 + row) * 192 + kc + g * 8);
            *(uint4*)(By + row * 128 + (((g ^ row) & 7) << 4)) = v;
        }
        __syncthreads();
#pragma unroll
        for (int ks = 0; ks < 2; ks++) {
            int gb = ks * 4 + kq;
            bf16x8 a[4], bb[2];
#pragma unroll
            for (int mt = 0; mt < 4; mt++) {
                int row = mt * 16 + ml;
                a[mt] = *(const bf16x8*)(Aw + row * 128 + (((gb ^ row) & 7) << 4));
            }
#pragma unroll
            for (int nt = 0; nt < 2; nt++) {
                int row = wn * 32 + nt * 16 + ml;
                bb[nt] = *(const bf16x8*)(By + row * 128 + (((gb ^ row) & 7) << 4));
            }
#pragma unroll
            for (int mt = 0; mt < 4; mt++)
#pragma unroll
                for (int nt = 0; nt < 2; nt++)
                    acc[mt][nt] = __builtin_amdgcn_mfma_f32_16x16x32_bf16(a[mt], bb[nt], acc[mt][nt], 0, 0, 0);
        }
        __syncthreads();
    }

#pragma unroll
    for (int mt = 0; mt < 4; mt++)
#pragma unroll
        for (int r = 0; r < 4; r++) {
            int d = d0 + mt * 16 + kq * 4 + r;
            float inv = gamma[d] * rsqrtf(var[d] + 1e-5f);
            float bias = b_ff[d], mu = mean[d], bt = beta[d];
#pragma unroll
            for (int nt = 0; nt < 2; nt++) {
                int p = p0 + wn * 32 + nt * 16 + ml;
                size_t xi = ((size_t)n * NCH + d) * TV + p;
                float v = acc[mt][nt][r] + bias;
                v = (v - mu) * inv + bt;
                float z = x[xi] + v;
                out[xi] = (z >= 0.f) ? z : 0.1f * z;
            }
        }
}

// ---------------------------------------------------------------------------
extern "C" void kernel_launch(void* const* d_in, const int* in_sizes, int n_in,
                              void* d_out, int out_size, void* d_ws, size_t ws_size,
                              hipStream_t stream) {
    const float* x     = (const float*)d_in[0];
    const float* w_in  = (const float*)d_in[1];
    const float* b_in  = (const float*)d_in[2];
    const float* w_ff  = (const float*)d_in[3];
    const float* b_ff  = (const float*)d_in[4];
    const float* gamma = (const float*)d_in[5];
    const float* beta  = (const float*)d_in[6];
    const float* mean  = (const float*)d_in[7];
    const float* var   = (const float*)d_in[8];

    // ws: qkv bf16 [0,235929600) | att bf16 [..,248512512) | x_t/y_t bf16 (aliased,
    // x_t dead before k_av writes y_t) [..,327155712) | w_bf [..,327450624)
    u16* qkv = (u16*)d_ws;
    u16* att = (u16*)((char*)d_ws + 235929600ull);
    u16* x_t = (u16*)((char*)d_ws + 248512512ull);
    u16* y_t = x_t;
    u32* wb  = (u32*)((char*)d_ws + 327155712ull);
    u16* w_inb = (u16*)wb;
    u16* w_ffb = w_inb + 110592;
    // d_out doubles as scratch for qt/kt (exact fit); k_ff overwrites it last.
    u16* qt = (u16*)d_out;
    u16* kt = qt + 39321600ull;
    float* out = (float*)d_out;

    k_wcast <<<dim3(288),       dim3(256), 0, stream>>>(w_in, w_ff, wb);
    k_trx   <<<dim3(50, 3, 32), dim3(256), 0, stream>>>(x, x_t);
    k_qkv   <<<dim3(50, 32),    dim3(256), 0, stream>>>(x_t, w_inb, b_in, qkv);
    k_tr    <<<dim3(16, 6, 32), dim3(256), 0, stream>>>(qkv, qt, kt);
    k_scores<<<dim3(4, 2, 96),  dim3(256), 0, stream>>>(qt, kt, att);
    k_av    <<<dim3(25, 2, 96), dim3(256), 0, stream>>>(qkv, att, y_t);
    k_ff    <<<dim3(50, 3, 32), dim3(256), 0, stream>>>(y_t, x, w_ffb, b_ff, gamma, beta, mean, var, out);
}